// Round 9
// baseline (269.535 us; speedup 1.0000x reference)
//
#include <hip/hip_runtime.h>
#include <hip/hip_fp16.h>

// VectorBasis R9. R8 structure (2 kernels, direct out overwrite) with the
// counting-sort machinery replaced by fixed-stride slot scatter in BOTH
// phases: one LDS atomic per record (its return value IS the slot), no
// histogram pass, no scan, no sorted-srec movement (R8: 2 atomics/record +
// 2M bank-conflict cycles). Overflow (slot >= stride, Poisson tail) goes to
// the global spill list phase2 already scans.

constexpr int NSP  = 4;
constexpr int NRAD = 8;
constexpr int NPS  = 4;
constexpr int DDIM = NRAD * NPS;       // 32

constexpr int APB      = 128;          // atoms per bin
constexpr int APB_SH   = 7;
constexpr int NBIN_PAD = 832;
constexpr int PH1_BLK  = 512;
constexpr int PH1_U    = 4;
constexpr int PH1_REC  = PH1_BLK * PH1_U;  // 2048
constexpr int S1       = 9;            // phase1 slots per bin (lambda 2.62)
constexpr int CAP2     = 2304;         // phase2 LDS chunk (records)
constexpr int S2       = 32;           // phase2 slots per atom per chunk
constexpr int OVF_CAP  = 65536;

__device__ __forceinline__ unsigned pack2(float a, float b) {
    union { __half2 h; unsigned u; } cv;
    cv.h = __floats2half2_rn(a, b);
    return cv.u;
}
__device__ __forceinline__ float2 unpack2(unsigned u) {
    union { unsigned u; __half2 h; } cv;
    cv.u = u;
    return __half22float2(cv.h);
}

__device__ __forceinline__ void build_w2(
    float* sW2, const float* cemb, const float* Wc, const float* W_alch,
    int tid, int nthreads)
{
    for (int i = tid; i < 3 * NRAD * 16; i += nthreads) {
        int p  = i & 15;
        int n  = (i >> 4) & 7;
        int o  = i >> 7;
        int sc = p >> 2, sn = p & 3;
        float w = 0.0f;
        #pragma unroll
        for (int q = 0; q < NPS; q++)
            w += cemb[sc * DDIM + n * NPS + q] * Wc[o * DDIM + n * NPS + q]
               * W_alch[sn * NPS + q];
        sW2[i] = w;
    }
}

__device__ __forceinline__ bool edge_math(
    float vx, float vy, float vz, int pair, const float* sW2,
    float g[3], float t[3])
{
    float d2    = vx * vx + vy * vy + vz * vz + 1e-12f;
    float d     = sqrtf(d2);
    float inv_d = 1.0f / d;

    const float PI = 3.14159265358979323846f;
    const float RCUT = 5.0f, INNER = 4.5f, INVW = 2.0f;
    if (d >= RCUT) return false;
    float taper = 0.5f * (cosf(PI * (d - INNER) * INVW) + 1.0f);
    float fc = (d < INNER) ? 1.0f : taper;

    float theta = (PI / RCUT) * d;
    float s1 = sinf(theta);
    float c1 = cosf(theta);
    float two_c = 2.0f * c1;
    float R[NRAD];
    R[0] = s1 * inv_d;
    float sm2 = 0.0f, sm1 = s1;
    #pragma unroll
    for (int n = 1; n < NRAD; n++) {
        float s = two_c * sm1 - sm2;
        sm2 = sm1; sm1 = s;
        R[n] = s * inv_d;
    }

    #pragma unroll
    for (int o = 0; o < 3; o++) {
        float acc = 0.0f;
        #pragma unroll
        for (int n = 0; n < NRAD; n++)
            acc += R[n] * sW2[(o * NRAD + n) * 16 + pair];
        t[o] = acc;
    }
    g[0] = fc * vy * inv_d;
    g[1] = fc * vz * inv_d;
    g[2] = fc * vx * inv_d;
    return true;
}

__device__ __forceinline__ void ovf_append(int* ovfcnt, int4* ovf, int4 r) {
    int p = atomicAdd(ovfcnt, 1);
    if (p < OVF_CAP) ovf[p] = r;
}

// ============ phase1: fixed-stride slot scatter, 1 LDS atomic/record ========
__global__ __launch_bounds__(PH1_BLK) void vb_phase1(
    const float* __restrict__ vecs,
    const int*   __restrict__ centers,
    const int*   __restrict__ neighbors,
    const int*   __restrict__ species,
    const float* __restrict__ W_alch,
    const float* __restrict__ cemb,
    const float* __restrict__ Wc,
    int*         __restrict__ gcursor,   // (nbin)
    int*         __restrict__ ovfcnt,
    int4*        __restrict__ ovf,
    int4*        __restrict__ payload,   // (nbin, cap)
    int E, int nbin, int cap)
{
    __shared__ float sW2[3 * NRAD * 16];                 // 1.5 KB
    __shared__ int4  srec[PH1_REC];                      // 32 KB, producer idx
    __shared__ unsigned short sidx[NBIN_PAD * S1];       // 14.6 KB
    __shared__ unsigned lcntP[NBIN_PAD / 2];             // 1.6 KB packed u16
    __shared__ unsigned short lbase[NBIN_PAD];           // 1.6 KB

    int tid = threadIdx.x;
    build_w2(sW2, cemb, Wc, W_alch, tid, PH1_BLK);
    for (int i = tid; i < NBIN_PAD / 2; i += PH1_BLK) lcntP[i] = 0;
    __syncthreads();

    // compute + single-atomic slot scatter
    #pragma unroll
    for (int u = 0; u < PH1_U; u++) {
        int e = blockIdx.x * PH1_REC + u * PH1_BLK + tid;
        if (e < E) {
            float vx = vecs[3 * e + 0];
            float vy = vecs[3 * e + 1];
            float vz = vecs[3 * e + 2];
            int c  = centers[e];
            int pair = species[c] * 4 + species[neighbors[e]];
            float g[3], t[3];
            if (edge_math(vx, vy, vz, pair, sW2, g, t)) {
                int4 r;
                r.x = c;
                r.y = (int)pack2(g[0], g[1]);
                r.z = (int)pack2(g[2], t[0]);
                r.w = (int)pack2(t[1], t[2]);
                int bin = c >> APB_SH;
                int sh  = (bin & 1) << 4;
                unsigned old = atomicAdd(&lcntP[bin >> 1], 1u << sh);
                int slot = (old >> sh) & 0xffff;
                if (slot < S1) {
                    int pidx = u * PH1_BLK + tid;
                    srec[pidx] = r;
                    sidx[bin * S1 + slot] = (unsigned short)pidx;
                } else {
                    ovf_append(ovfcnt, ovf, r);   // Poisson tail, ~1e3/launch
                }
            }
        }
    }
    __syncthreads();

    // global slot reservation (1 atomic per non-empty bin)
    for (int b = tid; b < nbin; b += PH1_BLK) {
        int n = (lcntP[b >> 1] >> ((b & 1) << 4)) & 0xffff;
        n = min(n, S1);
        if (n) lbase[b] = (unsigned short)atomicAdd(&gcursor[b], n);
    }
    __syncthreads();

    // slot-space writeout: contiguous per-bin runs, coalesced-ish
    int slots = nbin * S1;
    for (int i = tid; i < slots; i += PH1_BLK) {
        unsigned bin = ((unsigned)i * 7282u) >> 16;   // i/9, exact for i<294912
        int j = i - (int)bin * S1;
        int n = (lcntP[bin >> 1] >> ((bin & 1) << 4)) & 0xffff;
        if (j < min(n, S1)) {
            int4 r = srec[sidx[i]];
            int slot = (int)lbase[bin] + j;
            if (slot < cap)
                payload[(size_t)bin * cap + slot] = r;
            else
                ovf_append(ovfcnt, ovf, r);
        }
    }
}

// ====== phase2: per-bin fixed-stride scatter + direct out overwrite =========
__global__ __launch_bounds__(256) void vb_phase2(
    const int*  __restrict__ gcursor,
    const int*  __restrict__ ovfcnt,
    const int4* __restrict__ ovf,
    const int4* __restrict__ payload,
    float*      __restrict__ out,        // (A,9), fully overwritten
    int A, int cap)
{
    __shared__ int4 srec2[CAP2];                    // 36.9 KB
    __shared__ unsigned short sidx2[S2 * APB];      // 8 KB, slot-major
    __shared__ int cnt2[APB];                       // 0.5 KB
    __shared__ float sout[APB * 9];                 // 4.5 KB
    __shared__ int sflag;

    int b   = blockIdx.x;
    int tid = threadIdx.x;
    int count = min(gcursor[b], cap);
    const int4* pb = payload + (size_t)b * cap;

    float acc[9] = {0,0,0,0,0,0,0,0,0};
    int myatom = (b << APB_SH) + tid;   // tid < APB only

    for (int base = 0; base < count; base += CAP2) {
        int nc = min(count - base, CAP2);
        if (tid < APB) cnt2[tid] = 0;
        if (tid == 0) sflag = 0;
        __syncthreads();

        // load + single-atomic slot scatter
        for (int i = tid; i < nc; i += 256) {
            int4 r = pb[base + i];
            srec2[i] = r;
            int k = r.x & (APB - 1);
            int slot = atomicAdd(&cnt2[k], 1);
            if (slot < S2) sidx2[slot * APB + k] = (unsigned short)i;
            else sflag = 1;
        }
        __syncthreads();

        // per-atom register accumulation
        if (tid < APB) {
            int n = cnt2[tid];
            if (n <= S2) {
                for (int j = 0; j < n; j++) {
                    int4 r = srec2[sidx2[j * APB + tid]];
                    float2 g01 = unpack2((unsigned)r.y);
                    float2 g2t = unpack2((unsigned)r.z);
                    float2 t12 = unpack2((unsigned)r.w);
                    float g0 = g01.x, g1 = g01.y, g2 = g2t.x;
                    float t0 = g2t.y, t1 = t12.x, t2 = t12.y;
                    acc[0] += g0 * t0; acc[1] += g0 * t1; acc[2] += g0 * t2;
                    acc[3] += g1 * t0; acc[4] += g1 * t1; acc[5] += g1 * t2;
                    acc[6] += g2 * t0; acc[7] += g2 * t1; acc[8] += g2 * t2;
                }
            }
        }
        if (sflag) {
            // rare: some atom exceeded S2 slots -> its owner scans the chunk
            if (tid < APB && cnt2[tid] > S2) {
                for (int j = 0; j < nc; j++) {
                    int4 r = srec2[j];
                    if ((r.x & (APB - 1)) == tid) {
                        float2 g01 = unpack2((unsigned)r.y);
                        float2 g2t = unpack2((unsigned)r.z);
                        float2 t12 = unpack2((unsigned)r.w);
                        float g0 = g01.x, g1 = g01.y, g2 = g2t.x;
                        float t0 = g2t.y, t1 = t12.x, t2 = t12.y;
                        acc[0] += g0 * t0; acc[1] += g0 * t1; acc[2] += g0 * t2;
                        acc[3] += g1 * t0; acc[4] += g1 * t1; acc[5] += g1 * t2;
                        acc[6] += g2 * t0; acc[7] += g2 * t1; acc[8] += g2 * t2;
                    }
                }
            }
        }
        __syncthreads();   // srec2/sidx2 reused next chunk
    }

    // global overflow list (Poisson tail): broadcast scan
    int novf = min(*ovfcnt, OVF_CAP);
    for (int i = 0; i < novf; i++) {
        int4 r = ovf[i];
        if (tid < APB && r.x == myatom) {
            float2 g01 = unpack2((unsigned)r.y);
            float2 g2t = unpack2((unsigned)r.z);
            float2 t12 = unpack2((unsigned)r.w);
            float g0 = g01.x, g1 = g01.y, g2 = g2t.x;
            float t0 = g2t.y, t1 = t12.x, t2 = t12.y;
            acc[0] += g0 * t0; acc[1] += g0 * t1; acc[2] += g0 * t2;
            acc[3] += g1 * t0; acc[4] += g1 * t1; acc[5] += g1 * t2;
            acc[6] += g2 * t0; acc[7] += g2 * t1; acc[8] += g2 * t2;
        }
    }

    if (tid < APB) {
        #pragma unroll
        for (int k = 0; k < 9; k++) sout[tid * 9 + k] = acc[k];
    }
    __syncthreads();
    size_t gbase = (size_t)b * APB * 9;
    size_t lim = (size_t)A * 9;
    for (int i = tid; i < APB * 9; i += 256) {
        size_t gi = gbase + i;
        if (gi < lim) out[gi] = sout[i];
    }
}

// Fallback: direct per-edge global atomics (correct, slow).
__global__ __launch_bounds__(256) void vb_edge_fallback(
    const float* __restrict__ vecs,
    const int*   __restrict__ centers,
    const int*   __restrict__ neighbors,
    const int*   __restrict__ species,
    const float* __restrict__ W_alch,
    const float* __restrict__ cemb,
    const float* __restrict__ Wc,
    float*       __restrict__ out,
    int E)
{
    __shared__ float sW2[3 * NRAD * 16];
    build_w2(sW2, cemb, Wc, W_alch, threadIdx.x, blockDim.x);
    __syncthreads();

    int e = blockIdx.x * blockDim.x + threadIdx.x;
    if (e >= E) return;
    float vx = vecs[3 * e + 0], vy = vecs[3 * e + 1], vz = vecs[3 * e + 2];
    int c = centers[e];
    int pair = species[c] * 4 + species[neighbors[e]];
    float g[3], t[3];
    if (!edge_math(vx, vy, vz, pair, sW2, g, t)) return;
    float* op = out + (size_t)c * 9;
    #pragma unroll
    for (int m = 0; m < 3; m++)
        #pragma unroll
        for (int o = 0; o < 3; o++)
            atomicAdd(op + m * 3 + o, g[m] * t[o]);
}

extern "C" void kernel_launch(void* const* d_in, const int* in_sizes, int n_in,
                              void* d_out, int out_size, void* d_ws, size_t ws_size,
                              hipStream_t stream) {
    const float* vecs      = (const float*)d_in[0];
    const int*   centers   = (const int*)d_in[1];
    const int*   neighbors = (const int*)d_in[2];
    const int*   species   = (const int*)d_in[3];
    const float* W_alch    = (const float*)d_in[6];
    const float* cemb      = (const float*)d_in[7];
    const float* Wc        = (const float*)d_in[8];
    float*       out       = (float*)d_out;

    int E = in_sizes[1];
    int A = in_sizes[3];
    int nbin = (A + APB - 1) >> APB_SH;

    // ws: [gcursor nbin ints | ovfcnt @3840 | pad to 4KB][ovf 1MB][payload]
    size_t ovf_off = 4096;
    size_t pay_off = ovf_off + (size_t)OVF_CAP * 16;
    long cap = 0;
    if (ws_size > pay_off) {
        cap = (long)((ws_size - pay_off) / 16) / nbin;
        cap &= ~7L;
        if (cap > 4096) cap = 4096;
    }
    long mean = (long)E / nbin + 1;

    if (nbin <= NBIN_PAD && nbin <= 3840 / 4 && cap >= mean + mean / 8) {
        int*  gcursor = (int*)d_ws;
        int*  ovfcnt  = (int*)((char*)d_ws + 3840);
        int4* ovf     = (int4*)((char*)d_ws + ovf_off);
        int4* payload = (int4*)((char*)d_ws + pay_off);
        hipMemsetAsync(d_ws, 0, 4096, stream);

        int g1 = (E + PH1_REC - 1) / PH1_REC;
        vb_phase1<<<g1, PH1_BLK, 0, stream>>>(vecs, centers, neighbors, species,
                                              W_alch, cemb, Wc,
                                              gcursor, ovfcnt, ovf, payload,
                                              E, nbin, (int)cap);
        vb_phase2<<<nbin, 256, 0, stream>>>(gcursor, ovfcnt, ovf, payload,
                                            out, A, (int)cap);
    } else {
        hipMemsetAsync(d_out, 0, (size_t)out_size * sizeof(float), stream);
        int grid = (E + 255) / 256;
        vb_edge_fallback<<<grid, 256, 0, stream>>>(vecs, centers, neighbors, species,
                                                   W_alch, cemb, Wc, out, E);
    }
}

// Round 10
// 147.086 us; speedup vs baseline: 1.8325x; 1.8325x over previous
//
#include <hip/hip_runtime.h>
#include <hip/hip_fp16.h>

// VectorBasis R10. Best-known = R8 (144us). R9's lesson: rare-path overflow
// lists scanned by every block are a disaster; fixed-stride slots don't pay.
// R10 = R8 with phase1 restructured to be atomic-free and fully coalesced:
//   phase1 block -> private payload chunk [blk*2048, +total), records sorted
//   by bin (R8's proven LDS counting sort), plus u16 offset table
//   runoff[blk][bin] (start of bin's run; [nbin]=total). No gcursor, no
//   overflow (total<=2048=chunk), no memset node.
//   phase2 (per 128-atom bin, R8's proven sort+register accumulate) gathers
//   its runs from all chunks via the L2-resident offset table.

constexpr int NSP  = 4;
constexpr int NRAD = 8;
constexpr int NPS  = 4;
constexpr int DDIM = NRAD * NPS;       // 32

constexpr int APB       = 128;         // atoms per bin
constexpr int APB_SH    = 7;
constexpr int NBIN_PAD  = 832;         // 64*13, >= nbin(782)
constexpr int NROWS_PAD = 832;         // >= nblocks(782)
constexpr int RS        = 840;         // runoff row stride (u16s), >= nbin+1
constexpr int PH1_BLK   = 512;
constexpr int PH1_U     = 4;
constexpr int PH1_REC   = PH1_BLK * PH1_U;  // 2048
constexpr int CAP2      = 2304;        // phase2 LDS chunk (records)

__device__ __forceinline__ unsigned pack2(float a, float b) {
    union { __half2 h; unsigned u; } cv;
    cv.h = __floats2half2_rn(a, b);
    return cv.u;
}
__device__ __forceinline__ float2 unpack2(unsigned u) {
    union { unsigned u; __half2 h; } cv;
    cv.u = u;
    return __half22float2(cv.h);
}

__device__ __forceinline__ void build_w2(
    float* sW2, const float* cemb, const float* Wc, const float* W_alch,
    int tid, int nthreads)
{
    for (int i = tid; i < 3 * NRAD * 16; i += nthreads) {
        int p  = i & 15;
        int n  = (i >> 4) & 7;
        int o  = i >> 7;
        int sc = p >> 2, sn = p & 3;
        float w = 0.0f;
        #pragma unroll
        for (int q = 0; q < NPS; q++)
            w += cemb[sc * DDIM + n * NPS + q] * Wc[o * DDIM + n * NPS + q]
               * W_alch[sn * NPS + q];
        sW2[i] = w;
    }
}

__device__ __forceinline__ bool edge_math(
    float vx, float vy, float vz, int pair, const float* sW2,
    float g[3], float t[3])
{
    float d2    = vx * vx + vy * vy + vz * vz + 1e-12f;
    float d     = sqrtf(d2);
    float inv_d = 1.0f / d;

    const float PI = 3.14159265358979323846f;
    const float RCUT = 5.0f, INNER = 4.5f, INVW = 2.0f;
    if (d >= RCUT) return false;
    float taper = 0.5f * (cosf(PI * (d - INNER) * INVW) + 1.0f);
    float fc = (d < INNER) ? 1.0f : taper;

    float theta = (PI / RCUT) * d;
    float s1 = sinf(theta);
    float c1 = cosf(theta);
    float two_c = 2.0f * c1;
    float R[NRAD];
    R[0] = s1 * inv_d;
    float sm2 = 0.0f, sm1 = s1;
    #pragma unroll
    for (int n = 1; n < NRAD; n++) {
        float s = two_c * sm1 - sm2;
        sm2 = sm1; sm1 = s;
        R[n] = s * inv_d;
    }

    #pragma unroll
    for (int o = 0; o < 3; o++) {
        float acc = 0.0f;
        #pragma unroll
        for (int n = 0; n < NRAD; n++)
            acc += R[n] * sW2[(o * NRAD + n) * 16 + pair];
        t[o] = acc;
    }
    g[0] = fc * vy * inv_d;
    g[1] = fc * vz * inv_d;
    g[2] = fc * vx * inv_d;
    return true;
}

// ====== phase1: block-private sorted chunk + offset table, no atomics =======
__global__ __launch_bounds__(PH1_BLK) void vb_phase1(
    const float* __restrict__ vecs,
    const int*   __restrict__ centers,
    const int*   __restrict__ neighbors,
    const int*   __restrict__ species,
    const float* __restrict__ W_alch,
    const float* __restrict__ cemb,
    const float* __restrict__ Wc,
    unsigned short* __restrict__ runoff,  // (nblocks, RS)
    int4*        __restrict__ payload,    // (nblocks, PH1_REC)
    int E, int nbin)
{
    __shared__ float sW2[3 * NRAD * 16];   // 1.5 KB
    __shared__ int4  srec[PH1_REC];        // 32 KB
    __shared__ int   lcount[NBIN_PAD];     // 3.3 KB
    __shared__ int   lexcl[NBIN_PAD];      // 3.3 KB
    __shared__ int   lcur[NBIN_PAD];       // 3.3 KB
    __shared__ int   sTotal;

    int tid = threadIdx.x;
    build_w2(sW2, cemb, Wc, W_alch, tid, PH1_BLK);
    for (int i = tid; i < NBIN_PAD; i += PH1_BLK) lcount[i] = 0;
    __syncthreads();

    int4 rec[PH1_U];
    #pragma unroll
    for (int u = 0; u < PH1_U; u++) {
        int e = blockIdx.x * PH1_REC + u * PH1_BLK + tid;
        rec[u].x = -1;
        if (e < E) {
            float vx = vecs[3 * e + 0];
            float vy = vecs[3 * e + 1];
            float vz = vecs[3 * e + 2];
            int c  = centers[e];
            int pair = species[c] * 4 + species[neighbors[e]];
            float g[3], t[3];
            if (edge_math(vx, vy, vz, pair, sW2, g, t)) {
                rec[u].x = c;
                rec[u].y = (int)pack2(g[0], g[1]);
                rec[u].z = (int)pack2(g[2], t[0]);
                rec[u].w = (int)pack2(t[1], t[2]);
                atomicAdd(&lcount[c >> APB_SH], 1);
            }
        }
    }
    __syncthreads();

    // single-wave exclusive scan over NBIN_PAD bins (13/lane)
    if (tid < 64) {
        int base = tid * 13;
        int pre[13];
        int sum = 0;
        #pragma unroll
        for (int j = 0; j < 13; j++) { pre[j] = sum; sum += lcount[base + j]; }
        int incl = sum;
        #pragma unroll
        for (int off = 1; off < 64; off <<= 1) {
            int t = __shfl_up(incl, off, 64);
            if (tid >= off) incl += t;
        }
        int ex = incl - sum;
        #pragma unroll
        for (int j = 0; j < 13; j++) lexcl[base + j] = ex + pre[j];
        if (tid == 63) sTotal = incl;
    }
    __syncthreads();
    for (int i = tid; i < NBIN_PAD; i += PH1_BLK) lcur[i] = lexcl[i];
    __syncthreads();

    // scatter records into LDS sorted by bin (1 LDS atomic/record)
    #pragma unroll
    for (int u = 0; u < PH1_U; u++) {
        if (rec[u].x >= 0) {
            int bin = rec[u].x >> APB_SH;
            int p = atomicAdd(&lcur[bin], 1);
            srec[p] = rec[u];
        }
    }
    __syncthreads();

    // fully coalesced chunk dump + offset table
    int total = sTotal;
    size_t pbase = (size_t)blockIdx.x * PH1_REC;
    for (int i = tid; i < total; i += PH1_BLK)
        payload[pbase + i] = srec[i];
    unsigned short* ro = runoff + (size_t)blockIdx.x * RS;
    for (int b = tid; b <= nbin; b += PH1_BLK)
        ro[b] = (unsigned short)((b < nbin) ? lexcl[b] : total);
}

// ====== phase2: gather runs from all chunks, sort by atom, overwrite out ====
__global__ __launch_bounds__(256) void vb_phase2(
    const unsigned short* __restrict__ runoff,   // (nblocks, RS)
    const int4*           __restrict__ payload,  // (nblocks, PH1_REC)
    float*                __restrict__ out,      // (A,9), fully overwritten
    int A, int nblocks)
{
    __shared__ int4 srec2[CAP2];                    // 36.9 KB
    __shared__ unsigned short sidx[CAP2];           // 4.6 KB
    __shared__ unsigned short sst[NROWS_PAD];       // 1.6 KB, run start
    __shared__ unsigned short slen[NROWS_PAD];      // 1.6 KB, run length
    __shared__ unsigned short roff[NROWS_PAD];      // 1.6 KB, excl scan of len
    __shared__ int cnt[APB], aexcl[APB], ccur[APB]; // 1.5 KB
    __shared__ float sout[APB * 9];                 // 4.5 KB
    __shared__ int sTotal;

    int b   = blockIdx.x;
    int tid = threadIdx.x;

    // per-chunk run table for this bin (offset table is L2-resident, 1.3MB)
    for (int r = tid; r < NROWS_PAD; r += 256) {
        unsigned short s0 = 0, len = 0;
        if (r < nblocks) {
            const unsigned short* row = runoff + (size_t)r * RS + b;
            s0 = row[0];
            len = (unsigned short)(row[1] - row[0]);
        }
        sst[r] = s0;
        slen[r] = len;
    }
    __syncthreads();

    // single-wave exclusive scan over NROWS_PAD rows (13/lane)
    if (tid < 64) {
        int base = tid * 13;
        int pre[13];
        int sum = 0;
        #pragma unroll
        for (int j = 0; j < 13; j++) { pre[j] = sum; sum += slen[base + j]; }
        int incl = sum;
        #pragma unroll
        for (int off = 1; off < 64; off <<= 1) {
            int t = __shfl_up(incl, off, 64);
            if (tid >= off) incl += t;
        }
        int ex = incl - sum;
        #pragma unroll
        for (int j = 0; j < 13; j++)
            roff[base + j] = (unsigned short)(ex + pre[j]);
        if (tid == 63) sTotal = incl;
    }
    __syncthreads();

    int total = sTotal;
    float acc[9] = {0,0,0,0,0,0,0,0,0};

    // chunk loop (normally 1 iteration: total ~2048 <= CAP2)
    for (int w0 = 0; w0 < total; w0 += CAP2) {
        int wend = min(w0 + CAP2, total);
        int nc = wend - w0;

        // windowed gather of runs into LDS
        for (int r = tid; r < nblocks; r += 256) {
            int len = slen[r];
            int ro  = roff[r];
            if (len && ro < wend && ro + len > w0) {
                int j0 = max(0, w0 - ro);
                int j1 = min(len, wend - ro);
                const int4* src = payload + (size_t)r * PH1_REC + sst[r];
                for (int j = j0; j < j1; j++)
                    srec2[ro + j - w0] = src[j];
            }
        }
        if (tid < APB) cnt[tid] = 0;
        __syncthreads();

        // histogram by atom (1 LDS atomic/record)
        for (int i = tid; i < nc; i += 256)
            atomicAdd(&cnt[srec2[i].x & (APB - 1)], 1);
        __syncthreads();

        // single-wave exclusive scan over 128 keys (2/lane)
        if (tid < 64) {
            int c0 = cnt[2 * tid], c1 = cnt[2 * tid + 1];
            int s1 = c0 + c1;
            int incl = s1;
            #pragma unroll
            for (int off = 1; off < 64; off <<= 1) {
                int t = __shfl_up(incl, off, 64);
                if (tid >= off) incl += t;
            }
            int ex = incl - s1;
            aexcl[2 * tid]     = ex;
            aexcl[2 * tid + 1] = ex + c0;
        }
        __syncthreads();
        if (tid < APB) ccur[tid] = aexcl[tid];
        __syncthreads();

        // scatter indices sorted by atom (1 LDS atomic/record)
        for (int i = tid; i < nc; i += 256) {
            int k = srec2[i].x & (APB - 1);
            sidx[atomicAdd(&ccur[k], 1)] = (unsigned short)i;
        }
        __syncthreads();

        // per-atom register accumulation (threads 0..127 own one atom each)
        if (tid < APB) {
            int st = aexcl[tid], en = st + cnt[tid];
            for (int j = st; j < en; j++) {
                int4 r = srec2[sidx[j]];
                float2 g01 = unpack2((unsigned)r.y);
                float2 g2t = unpack2((unsigned)r.z);
                float2 t12 = unpack2((unsigned)r.w);
                float g0 = g01.x, g1 = g01.y, g2 = g2t.x;
                float t0 = g2t.y, t1 = t12.x, t2 = t12.y;
                acc[0] += g0 * t0; acc[1] += g0 * t1; acc[2] += g0 * t2;
                acc[3] += g1 * t0; acc[4] += g1 * t1; acc[5] += g1 * t2;
                acc[6] += g2 * t0; acc[7] += g2 * t1; acc[8] += g2 * t2;
            }
        }
        __syncthreads();   // srec2/sidx reused next chunk
    }

    // direct coalesced overwrite of out
    if (tid < APB) {
        #pragma unroll
        for (int k = 0; k < 9; k++) sout[tid * 9 + k] = acc[k];
    }
    __syncthreads();
    size_t gbase = (size_t)b * APB * 9;
    size_t lim = (size_t)A * 9;
    for (int i = tid; i < APB * 9; i += 256) {
        size_t gi = gbase + i;
        if (gi < lim) out[gi] = sout[i];
    }
}

// Fallback: direct per-edge global atomics (correct, slow).
__global__ __launch_bounds__(256) void vb_edge_fallback(
    const float* __restrict__ vecs,
    const int*   __restrict__ centers,
    const int*   __restrict__ neighbors,
    const int*   __restrict__ species,
    const float* __restrict__ W_alch,
    const float* __restrict__ cemb,
    const float* __restrict__ Wc,
    float*       __restrict__ out,
    int E)
{
    __shared__ float sW2[3 * NRAD * 16];
    build_w2(sW2, cemb, Wc, W_alch, threadIdx.x, blockDim.x);
    __syncthreads();

    int e = blockIdx.x * blockDim.x + threadIdx.x;
    if (e >= E) return;
    float vx = vecs[3 * e + 0], vy = vecs[3 * e + 1], vz = vecs[3 * e + 2];
    int c = centers[e];
    int pair = species[c] * 4 + species[neighbors[e]];
    float g[3], t[3];
    if (!edge_math(vx, vy, vz, pair, sW2, g, t)) return;
    float* op = out + (size_t)c * 9;
    #pragma unroll
    for (int m = 0; m < 3; m++)
        #pragma unroll
        for (int o = 0; o < 3; o++)
            atomicAdd(op + m * 3 + o, g[m] * t[o]);
}

extern "C" void kernel_launch(void* const* d_in, const int* in_sizes, int n_in,
                              void* d_out, int out_size, void* d_ws, size_t ws_size,
                              hipStream_t stream) {
    const float* vecs      = (const float*)d_in[0];
    const int*   centers   = (const int*)d_in[1];
    const int*   neighbors = (const int*)d_in[2];
    const int*   species   = (const int*)d_in[3];
    const float* W_alch    = (const float*)d_in[6];
    const float* cemb      = (const float*)d_in[7];
    const float* Wc        = (const float*)d_in[8];
    float*       out       = (float*)d_out;

    int E = in_sizes[1];
    int A = in_sizes[3];
    int nbin    = (A + APB - 1) >> APB_SH;
    int nblocks = (E + PH1_REC - 1) / PH1_REC;

    // ws: [runoff nblocks*RS u16][payload nblocks*2048*16B]
    size_t ro_bytes = ((size_t)nblocks * RS * 2 + 255) & ~(size_t)255;
    size_t need = ro_bytes + (size_t)nblocks * PH1_REC * 16;

    if (nbin + 1 <= RS && nbin <= NBIN_PAD && nblocks <= NROWS_PAD &&
        need <= ws_size) {
        unsigned short* runoff = (unsigned short*)d_ws;
        int4* payload = (int4*)((char*)d_ws + ro_bytes);

        vb_phase1<<<nblocks, PH1_BLK, 0, stream>>>(vecs, centers, neighbors,
                                                   species, W_alch, cemb, Wc,
                                                   runoff, payload, E, nbin);
        vb_phase2<<<nbin, 256, 0, stream>>>(runoff, payload, out, A, nblocks);
    } else {
        hipMemsetAsync(d_out, 0, (size_t)out_size * sizeof(float), stream);
        int grid = (E + 255) / 256;
        vb_edge_fallback<<<grid, 256, 0, stream>>>(vecs, centers, neighbors,
                                                   species, W_alch, cemb, Wc,
                                                   out, E);
    }
}

// Round 11
// 133.431 us; speedup vs baseline: 2.0200x; 1.1023x over previous
//
#include <hip/hip_runtime.h>
#include <hip/hip_fp16.h>

// VectorBasis R11. Discovery (R10 profile): top dispatches are the harness's
// 256MiB d_ws poison fills (~45us @6TB/s) -> ~52us of wall is fixed harness
// overhead; kernels total ~95us. Structure kept from R10 (2 kernels,
// block-private sorted chunks + offset table, direct out overwrite). Changes:
//  - phase1 LDS 48->37KB (packed u16 count/cursor, reuse hist as cursor)
//    -> 4 blocks/CU.
//  - phase2 gather is record-parallel: binary search run table in LDS, then
//    COALESCED payload reads (R10: per-run scattered 16B loads, lambda=2.6).
//    CAP2 1536 -> 4 blocks/CU. Accumulation split 2 threads/atom.

constexpr int NSP  = 4;
constexpr int NRAD = 8;
constexpr int NPS  = 4;
constexpr int DDIM = NRAD * NPS;       // 32

constexpr int APB       = 128;         // atoms per bin
constexpr int APB_SH    = 7;
constexpr int NBIN_PAD  = 832;         // 64*13 >= nbin(782)
constexpr int NROWS_PAD = 832;         // >= nblocks(782)
constexpr int RS        = 840;         // runoff row stride (u16), >= nbin+1
constexpr int PH1_BLK   = 512;
constexpr int PH1_U     = 4;
constexpr int PH1_REC   = PH1_BLK * PH1_U;  // 2048
constexpr int CAP2      = 1536;        // phase2 LDS chunk (records)

__device__ __forceinline__ unsigned pack2(float a, float b) {
    union { __half2 h; unsigned u; } cv;
    cv.h = __floats2half2_rn(a, b);
    return cv.u;
}
__device__ __forceinline__ float2 unpack2(unsigned u) {
    union { unsigned u; __half2 h; } cv;
    cv.u = u;
    return __half22float2(cv.h);
}

__device__ __forceinline__ void build_w2(
    float* sW2, const float* cemb, const float* Wc, const float* W_alch,
    int tid, int nthreads)
{
    for (int i = tid; i < 3 * NRAD * 16; i += nthreads) {
        int p  = i & 15;
        int n  = (i >> 4) & 7;
        int o  = i >> 7;
        int sc = p >> 2, sn = p & 3;
        float w = 0.0f;
        #pragma unroll
        for (int q = 0; q < NPS; q++)
            w += cemb[sc * DDIM + n * NPS + q] * Wc[o * DDIM + n * NPS + q]
               * W_alch[sn * NPS + q];
        sW2[i] = w;
    }
}

__device__ __forceinline__ bool edge_math(
    float vx, float vy, float vz, int pair, const float* sW2,
    float g[3], float t[3])
{
    float d2    = vx * vx + vy * vy + vz * vz + 1e-12f;
    float d     = sqrtf(d2);
    float inv_d = 1.0f / d;

    const float PI = 3.14159265358979323846f;
    const float RCUT = 5.0f, INNER = 4.5f, INVW = 2.0f;
    if (d >= RCUT) return false;
    float taper = 0.5f * (cosf(PI * (d - INNER) * INVW) + 1.0f);
    float fc = (d < INNER) ? 1.0f : taper;

    float theta = (PI / RCUT) * d;
    float s1 = sinf(theta);
    float c1 = cosf(theta);
    float two_c = 2.0f * c1;
    float R[NRAD];
    R[0] = s1 * inv_d;
    float sm2 = 0.0f, sm1 = s1;
    #pragma unroll
    for (int n = 1; n < NRAD; n++) {
        float s = two_c * sm1 - sm2;
        sm2 = sm1; sm1 = s;
        R[n] = s * inv_d;
    }

    #pragma unroll
    for (int o = 0; o < 3; o++) {
        float acc = 0.0f;
        #pragma unroll
        for (int n = 0; n < NRAD; n++)
            acc += R[n] * sW2[(o * NRAD + n) * 16 + pair];
        t[o] = acc;
    }
    g[0] = fc * vy * inv_d;
    g[1] = fc * vz * inv_d;
    g[2] = fc * vx * inv_d;
    return true;
}

// ====== phase1: block-private sorted chunk + offset table ===================
__global__ __launch_bounds__(PH1_BLK) void vb_phase1(
    const float* __restrict__ vecs,
    const int*   __restrict__ centers,
    const int*   __restrict__ neighbors,
    const int*   __restrict__ species,
    const float* __restrict__ W_alch,
    const float* __restrict__ cemb,
    const float* __restrict__ Wc,
    unsigned short* __restrict__ runoff,  // (nblocks, RS)
    int4*        __restrict__ payload,    // (nblocks, PH1_REC)
    int E, int nbin)
{
    __shared__ float sW2[3 * NRAD * 16];        // 1.5 KB
    __shared__ int4  srec[PH1_REC];             // 32 KB
    __shared__ unsigned lcntP[NBIN_PAD / 2];    // 1.66 KB packed u16 pairs
    __shared__ unsigned short lexcl[NBIN_PAD];  // 1.66 KB
    __shared__ int sTotal;

    int tid = threadIdx.x;
    build_w2(sW2, cemb, Wc, W_alch, tid, PH1_BLK);
    for (int i = tid; i < NBIN_PAD / 2; i += PH1_BLK) lcntP[i] = 0;
    __syncthreads();

    int4 rec[PH1_U];
    #pragma unroll
    for (int u = 0; u < PH1_U; u++) {
        int e = blockIdx.x * PH1_REC + u * PH1_BLK + tid;
        rec[u].x = -1;
        if (e < E) {
            float vx = vecs[3 * e + 0];
            float vy = vecs[3 * e + 1];
            float vz = vecs[3 * e + 2];
            int c  = centers[e];
            int pair = species[c] * 4 + species[neighbors[e]];
            float g[3], t[3];
            if (edge_math(vx, vy, vz, pair, sW2, g, t)) {
                rec[u].x = c;
                rec[u].y = (int)pack2(g[0], g[1]);
                rec[u].z = (int)pack2(g[2], t[0]);
                rec[u].w = (int)pack2(t[1], t[2]);
                int bin = c >> APB_SH;
                atomicAdd(&lcntP[bin >> 1], 1u << ((bin & 1) << 4));
            }
        }
    }
    __syncthreads();

    // single-wave exclusive scan over NBIN_PAD bins (13/lane), packed counts
    if (tid < 64) {
        int base = tid * 13;
        int pre[13];
        int sum = 0;
        #pragma unroll
        for (int j = 0; j < 13; j++) {
            int b = base + j;
            int n = (lcntP[b >> 1] >> ((b & 1) << 4)) & 0xffff;
            pre[j] = sum; sum += n;
        }
        int incl = sum;
        #pragma unroll
        for (int off = 1; off < 64; off <<= 1) {
            int t = __shfl_up(incl, off, 64);
            if (tid >= off) incl += t;
        }
        int ex = incl - sum;
        #pragma unroll
        for (int j = 0; j < 13; j++)
            lexcl[base + j] = (unsigned short)(ex + pre[j]);
        if (tid == 63) sTotal = incl;
    }
    __syncthreads();
    // reuse lcntP as scatter cursor
    for (int i = tid; i < NBIN_PAD / 2; i += PH1_BLK) lcntP[i] = 0;
    __syncthreads();

    // scatter records into LDS sorted by bin (1 LDS atomic/record)
    #pragma unroll
    for (int u = 0; u < PH1_U; u++) {
        if (rec[u].x >= 0) {
            int bin = rec[u].x >> APB_SH;
            int sh  = (bin & 1) << 4;
            int slot = (int)((atomicAdd(&lcntP[bin >> 1], 1u << sh) >> sh) & 0xffff);
            srec[(int)lexcl[bin] + slot] = rec[u];
        }
    }
    __syncthreads();

    // fully coalesced chunk dump + offset table
    int total = sTotal;
    size_t pbase = (size_t)blockIdx.x * PH1_REC;
    for (int i = tid; i < total; i += PH1_BLK)
        payload[pbase + i] = srec[i];
    unsigned short* ro = runoff + (size_t)blockIdx.x * RS;
    for (int b = tid; b <= nbin; b += PH1_BLK)
        ro[b] = (b < nbin) ? lexcl[b] : (unsigned short)total;
}

// ====== phase2: binary-search coalesced gather, sort by atom, overwrite =====
__global__ __launch_bounds__(256) void vb_phase2(
    const unsigned short* __restrict__ runoff,   // (nblocks, RS)
    const int4*           __restrict__ payload,  // (nblocks, PH1_REC)
    float*                __restrict__ out,      // (A,9), fully overwritten
    int A, int nblocks)
{
    __shared__ int4 srec2[CAP2];                    // 24 KB
    __shared__ unsigned short sidx[CAP2];           // 3 KB
    __shared__ unsigned short sst[NROWS_PAD];       // 1.66 KB run start in chunk
    __shared__ unsigned short roff[NROWS_PAD + 64]; // 1.8 KB excl scan (+sentinel)
    __shared__ int cnt[APB], aexcl[APB], ccur[APB]; // 1.5 KB
    __shared__ float sout[APB * 9];                 // 4.5 KB
    __shared__ int sTotal;

    int b   = blockIdx.x;
    int tid = threadIdx.x;

    // run table for this bin: start-in-chunk and length per source block
    for (int r = tid; r < NROWS_PAD; r += 256) {
        unsigned short s0 = 0, len = 0;
        if (r < nblocks) {
            const unsigned short* row = runoff + (size_t)r * RS + b;
            s0  = row[0];
            len = (unsigned short)(row[1] - row[0]);
        }
        sst[r]  = s0;
        roff[r] = len;   // temporarily lengths; scanned in place below
    }
    __syncthreads();

    // single-wave exclusive scan over NROWS_PAD rows (13/lane)
    if (tid < 64) {
        int base = tid * 13;
        int pre[13];
        int sum = 0;
        #pragma unroll
        for (int j = 0; j < 13; j++) { pre[j] = sum; sum += roff[base + j]; }
        int incl = sum;
        #pragma unroll
        for (int off = 1; off < 64; off <<= 1) {
            int t = __shfl_up(incl, off, 64);
            if (tid >= off) incl += t;
        }
        int ex = incl - sum;
        #pragma unroll
        for (int j = 0; j < 13; j++)
            roff[base + j] = (unsigned short)(ex + pre[j]);
        if (tid == 63) sTotal = incl;
    }
    __syncthreads();
    if (tid == 0) roff[NROWS_PAD] = (unsigned short)sTotal;  // global sentinel
    // rows >= nblocks already have roff == total (zero-length suffix)
    __syncthreads();

    int total = sTotal;
    float acc[9] = {0,0,0,0,0,0,0,0,0};
    int half = tid >> 7;          // 0: first half of records, 1: second half
    int atom = tid & (APB - 1);   // each atom owned by 2 threads

    for (int w0 = 0; w0 < total; w0 += CAP2) {
        int wend = min(w0 + CAP2, total);
        int nc = wend - w0;

        // record-parallel gather: binary search the run, coalesced load
        for (int i = tid; i < nc; i += 256) {
            int p = w0 + i;
            int l = 0, h = nblocks;   // roff[l] <= p < roff[h]
            #pragma unroll 1
            while (h - l > 1) {
                int m = (l + h) >> 1;
                if ((int)roff[m] <= p) l = m; else h = m;
            }
            int j = p - (int)roff[l];
            srec2[i] = payload[(size_t)l * PH1_REC + (int)sst[l] + j];
        }
        if (tid < APB) cnt[tid] = 0;
        __syncthreads();

        // histogram by atom (1 LDS atomic/record)
        for (int i = tid; i < nc; i += 256)
            atomicAdd(&cnt[srec2[i].x & (APB - 1)], 1);
        __syncthreads();

        // single-wave exclusive scan over 128 keys (2/lane)
        if (tid < 64) {
            int c0 = cnt[2 * tid], c1 = cnt[2 * tid + 1];
            int s1 = c0 + c1;
            int incl = s1;
            #pragma unroll
            for (int off = 1; off < 64; off <<= 1) {
                int t = __shfl_up(incl, off, 64);
                if (tid >= off) incl += t;
            }
            int ex = incl - s1;
            aexcl[2 * tid]     = ex;
            aexcl[2 * tid + 1] = ex + c0;
        }
        __syncthreads();
        if (tid < APB) ccur[tid] = aexcl[tid];
        __syncthreads();

        // scatter indices sorted by atom (1 LDS atomic/record)
        for (int i = tid; i < nc; i += 256) {
            int k = srec2[i].x & (APB - 1);
            sidx[atomicAdd(&ccur[k], 1)] = (unsigned short)i;
        }
        __syncthreads();

        // accumulation: 2 threads per atom, each takes half the records
        {
            int st = aexcl[atom], n = cnt[atom];
            int mid = st + ((n + 1) >> 1);
            int lo = half ? mid : st;
            int hi = half ? (st + n) : mid;
            for (int j = lo; j < hi; j++) {
                int4 r = srec2[sidx[j]];
                float2 g01 = unpack2((unsigned)r.y);
                float2 g2t = unpack2((unsigned)r.z);
                float2 t12 = unpack2((unsigned)r.w);
                float g0 = g01.x, g1 = g01.y, g2 = g2t.x;
                float t0 = g2t.y, t1 = t12.x, t2 = t12.y;
                acc[0] += g0 * t0; acc[1] += g0 * t1; acc[2] += g0 * t2;
                acc[3] += g1 * t0; acc[4] += g1 * t1; acc[5] += g1 * t2;
                acc[6] += g2 * t0; acc[7] += g2 * t1; acc[8] += g2 * t2;
            }
        }
        __syncthreads();   // srec2/sidx reused next chunk
    }

    // combine the two halves and overwrite out (coalesced)
    if (half == 0) {
        #pragma unroll
        for (int k = 0; k < 9; k++) sout[atom * 9 + k] = acc[k];
    }
    __syncthreads();
    if (half == 1) {
        #pragma unroll
        for (int k = 0; k < 9; k++) sout[atom * 9 + k] += acc[k];
    }
    __syncthreads();
    size_t gbase = (size_t)b * APB * 9;
    size_t lim = (size_t)A * 9;
    for (int i = tid; i < APB * 9; i += 256) {
        size_t gi = gbase + i;
        if (gi < lim) out[gi] = sout[i];
    }
}

// Fallback: direct per-edge global atomics (correct, slow).
__global__ __launch_bounds__(256) void vb_edge_fallback(
    const float* __restrict__ vecs,
    const int*   __restrict__ centers,
    const int*   __restrict__ neighbors,
    const int*   __restrict__ species,
    const float* __restrict__ W_alch,
    const float* __restrict__ cemb,
    const float* __restrict__ Wc,
    float*       __restrict__ out,
    int E)
{
    __shared__ float sW2[3 * NRAD * 16];
    build_w2(sW2, cemb, Wc, W_alch, threadIdx.x, blockDim.x);
    __syncthreads();

    int e = blockIdx.x * blockDim.x + threadIdx.x;
    if (e >= E) return;
    float vx = vecs[3 * e + 0], vy = vecs[3 * e + 1], vz = vecs[3 * e + 2];
    int c = centers[e];
    int pair = species[c] * 4 + species[neighbors[e]];
    float g[3], t[3];
    if (!edge_math(vx, vy, vz, pair, sW2, g, t)) return;
    float* op = out + (size_t)c * 9;
    #pragma unroll
    for (int m = 0; m < 3; m++)
        #pragma unroll
        for (int o = 0; o < 3; o++)
            atomicAdd(op + m * 3 + o, g[m] * t[o]);
}

extern "C" void kernel_launch(void* const* d_in, const int* in_sizes, int n_in,
                              void* d_out, int out_size, void* d_ws, size_t ws_size,
                              hipStream_t stream) {
    const float* vecs      = (const float*)d_in[0];
    const int*   centers   = (const int*)d_in[1];
    const int*   neighbors = (const int*)d_in[2];
    const int*   species   = (const int*)d_in[3];
    const float* W_alch    = (const float*)d_in[6];
    const float* cemb      = (const float*)d_in[7];
    const float* Wc        = (const float*)d_in[8];
    float*       out       = (float*)d_out;

    int E = in_sizes[1];
    int A = in_sizes[3];
    int nbin    = (A + APB - 1) >> APB_SH;
    int nblocks = (E + PH1_REC - 1) / PH1_REC;

    // ws: [runoff nblocks*RS u16][payload nblocks*2048*16B]
    size_t ro_bytes = ((size_t)nblocks * RS * 2 + 255) & ~(size_t)255;
    size_t need = ro_bytes + (size_t)nblocks * PH1_REC * 16;

    if (nbin + 1 <= RS && nbin <= NBIN_PAD && nblocks <= NROWS_PAD &&
        need <= ws_size) {
        unsigned short* runoff = (unsigned short*)d_ws;
        int4* payload = (int4*)((char*)d_ws + ro_bytes);

        vb_phase1<<<nblocks, PH1_BLK, 0, stream>>>(vecs, centers, neighbors,
                                                   species, W_alch, cemb, Wc,
                                                   runoff, payload, E, nbin);
        vb_phase2<<<nbin, 256, 0, stream>>>(runoff, payload, out, A, nblocks);
    } else {
        hipMemsetAsync(d_out, 0, (size_t)out_size * sizeof(float), stream);
        int grid = (E + 255) / 256;
        vb_edge_fallback<<<grid, 256, 0, stream>>>(vecs, centers, neighbors,
                                                   species, W_alch, cemb, Wc,
                                                   out, E);
    }
}

// Round 12
// 130.585 us; speedup vs baseline: 2.0641x; 1.0218x over previous
//
#include <hip/hip_runtime.h>
#include <hip/hip_fp16.h>

// VectorBasis R12. R11 (133us) minus half the LDS atomics: the histogram
// atomicAdd's RETURN VALUE is the record's within-key arrival rank, so the
// scatter needs no second atomic — slot = excl[key] + rank. Ranks live in
// statically-indexed registers (phase1: PH1_U=4 unrolled; phase2: fixed
// 6-iter unrolled chunk pass) so nothing spills to scratch (R6 lesson).
// Remaining structure is R11-proven: block-private sorted chunks + u16
// offset table, binary-search coalesced gather, 2-thread/atom accumulate,
// direct out overwrite. Fixed harness overhead (~48us ws-poison fills)
// bounds the wall from below.

constexpr int NSP  = 4;
constexpr int NRAD = 8;
constexpr int NPS  = 4;
constexpr int DDIM = NRAD * NPS;       // 32

constexpr int APB       = 128;         // atoms per bin
constexpr int APB_SH    = 7;
constexpr int NBIN_PAD  = 832;         // 64*13 >= nbin(782)
constexpr int NROWS_PAD = 832;         // >= nblocks(782)
constexpr int RS        = 840;         // runoff row stride (u16), >= nbin+1
constexpr int PH1_BLK   = 512;
constexpr int PH1_U     = 4;
constexpr int PH1_REC   = PH1_BLK * PH1_U;  // 2048
constexpr int CAP2      = 1536;        // phase2 LDS chunk (records)
constexpr int IT2       = CAP2 / 256;  // 6 (static)

__device__ __forceinline__ unsigned pack2(float a, float b) {
    union { __half2 h; unsigned u; } cv;
    cv.h = __floats2half2_rn(a, b);
    return cv.u;
}
__device__ __forceinline__ float2 unpack2(unsigned u) {
    union { unsigned u; __half2 h; } cv;
    cv.u = u;
    return __half22float2(cv.h);
}

__device__ __forceinline__ void build_w2(
    float* sW2, const float* cemb, const float* Wc, const float* W_alch,
    int tid, int nthreads)
{
    for (int i = tid; i < 3 * NRAD * 16; i += nthreads) {
        int p  = i & 15;
        int n  = (i >> 4) & 7;
        int o  = i >> 7;
        int sc = p >> 2, sn = p & 3;
        float w = 0.0f;
        #pragma unroll
        for (int q = 0; q < NPS; q++)
            w += cemb[sc * DDIM + n * NPS + q] * Wc[o * DDIM + n * NPS + q]
               * W_alch[sn * NPS + q];
        sW2[i] = w;
    }
}

__device__ __forceinline__ bool edge_math(
    float vx, float vy, float vz, int pair, const float* sW2,
    float g[3], float t[3])
{
    float d2    = vx * vx + vy * vy + vz * vz + 1e-12f;
    float d     = sqrtf(d2);
    float inv_d = 1.0f / d;

    const float PI = 3.14159265358979323846f;
    const float RCUT = 5.0f, INNER = 4.5f, INVW = 2.0f;
    if (d >= RCUT) return false;
    float taper = 0.5f * (cosf(PI * (d - INNER) * INVW) + 1.0f);
    float fc = (d < INNER) ? 1.0f : taper;

    float theta = (PI / RCUT) * d;
    float s1 = sinf(theta);
    float c1 = cosf(theta);
    float two_c = 2.0f * c1;
    float R[NRAD];
    R[0] = s1 * inv_d;
    float sm2 = 0.0f, sm1 = s1;
    #pragma unroll
    for (int n = 1; n < NRAD; n++) {
        float s = two_c * sm1 - sm2;
        sm2 = sm1; sm1 = s;
        R[n] = s * inv_d;
    }

    #pragma unroll
    for (int o = 0; o < 3; o++) {
        float acc = 0.0f;
        #pragma unroll
        for (int n = 0; n < NRAD; n++)
            acc += R[n] * sW2[(o * NRAD + n) * 16 + pair];
        t[o] = acc;
    }
    g[0] = fc * vy * inv_d;
    g[1] = fc * vz * inv_d;
    g[2] = fc * vx * inv_d;
    return true;
}

// ====== phase1: block-private sorted chunk + offset table ===================
__global__ __launch_bounds__(PH1_BLK) void vb_phase1(
    const float* __restrict__ vecs,
    const int*   __restrict__ centers,
    const int*   __restrict__ neighbors,
    const int*   __restrict__ species,
    const float* __restrict__ W_alch,
    const float* __restrict__ cemb,
    const float* __restrict__ Wc,
    unsigned short* __restrict__ runoff,  // (nblocks, RS)
    int4*        __restrict__ payload,    // (nblocks, PH1_REC)
    int E, int nbin)
{
    __shared__ float sW2[3 * NRAD * 16];        // 1.5 KB
    __shared__ int4  srec[PH1_REC];             // 32 KB
    __shared__ unsigned lcntP[NBIN_PAD / 2];    // 1.66 KB packed u16 pairs
    __shared__ unsigned short lexcl[NBIN_PAD];  // 1.66 KB
    __shared__ int sTotal;

    int tid = threadIdx.x;
    build_w2(sW2, cemb, Wc, W_alch, tid, PH1_BLK);
    for (int i = tid; i < NBIN_PAD / 2; i += PH1_BLK) lcntP[i] = 0;
    __syncthreads();

    int4 rec[PH1_U];
    int  rnk[PH1_U];   // static indices only — stays in VGPRs
    #pragma unroll
    for (int u = 0; u < PH1_U; u++) {
        int e = blockIdx.x * PH1_REC + u * PH1_BLK + tid;
        rec[u].x = -1;
        rnk[u]   = 0;
        if (e < E) {
            float vx = vecs[3 * e + 0];
            float vy = vecs[3 * e + 1];
            float vz = vecs[3 * e + 2];
            int c  = centers[e];
            int pair = species[c] * 4 + species[neighbors[e]];
            float g[3], t[3];
            if (edge_math(vx, vy, vz, pair, sW2, g, t)) {
                rec[u].x = c;
                rec[u].y = (int)pack2(g[0], g[1]);
                rec[u].z = (int)pack2(g[2], t[0]);
                rec[u].w = (int)pack2(t[1], t[2]);
                int bin = c >> APB_SH;
                int sh  = (bin & 1) << 4;
                unsigned old = atomicAdd(&lcntP[bin >> 1], 1u << sh);
                rnk[u] = (int)((old >> sh) & 0xffff);   // arrival rank in bin
            }
        }
    }
    __syncthreads();

    // single-wave exclusive scan over NBIN_PAD bins (13/lane), packed counts
    if (tid < 64) {
        int base = tid * 13;
        int pre[13];
        int sum = 0;
        #pragma unroll
        for (int j = 0; j < 13; j++) {
            int b = base + j;
            int n = (lcntP[b >> 1] >> ((b & 1) << 4)) & 0xffff;
            pre[j] = sum; sum += n;
        }
        int incl = sum;
        #pragma unroll
        for (int off = 1; off < 64; off <<= 1) {
            int t = __shfl_up(incl, off, 64);
            if (tid >= off) incl += t;
        }
        int ex = incl - sum;
        #pragma unroll
        for (int j = 0; j < 13; j++)
            lexcl[base + j] = (unsigned short)(ex + pre[j]);
        if (tid == 63) sTotal = incl;
    }
    __syncthreads();

    // scatter records into LDS sorted by bin — NO atomic (slot = excl + rank)
    #pragma unroll
    for (int u = 0; u < PH1_U; u++) {
        if (rec[u].x >= 0) {
            int bin = rec[u].x >> APB_SH;
            srec[(int)lexcl[bin] + rnk[u]] = rec[u];
        }
    }
    __syncthreads();

    // fully coalesced chunk dump + offset table
    int total = sTotal;
    size_t pbase = (size_t)blockIdx.x * PH1_REC;
    for (int i = tid; i < total; i += PH1_BLK)
        payload[pbase + i] = srec[i];
    unsigned short* ro = runoff + (size_t)blockIdx.x * RS;
    for (int b = tid; b <= nbin; b += PH1_BLK)
        ro[b] = (b < nbin) ? lexcl[b] : (unsigned short)total;
}

// ====== phase2: binary-search coalesced gather, rank-sort, overwrite ========
__global__ __launch_bounds__(256) void vb_phase2(
    const unsigned short* __restrict__ runoff,   // (nblocks, RS)
    const int4*           __restrict__ payload,  // (nblocks, PH1_REC)
    float*                __restrict__ out,      // (A,9), fully overwritten
    int A, int nblocks)
{
    __shared__ int4 srec2[CAP2];                    // 24 KB
    __shared__ unsigned short sidx[CAP2];           // 3 KB
    __shared__ unsigned short sst[NROWS_PAD];       // 1.66 KB run start in chunk
    __shared__ unsigned short roff[NROWS_PAD + 64]; // 1.8 KB excl scan (+sentinel)
    __shared__ int cnt[APB], aexcl[APB];            // 1 KB
    __shared__ float sout[APB * 9];                 // 4.5 KB
    __shared__ int sTotal;

    int b   = blockIdx.x;
    int tid = threadIdx.x;

    // run table for this bin: start-in-chunk and length per source block
    for (int r = tid; r < NROWS_PAD; r += 256) {
        unsigned short s0 = 0, len = 0;
        if (r < nblocks) {
            const unsigned short* row = runoff + (size_t)r * RS + b;
            s0  = row[0];
            len = (unsigned short)(row[1] - row[0]);
        }
        sst[r]  = s0;
        roff[r] = len;   // temporarily lengths; scanned in place below
    }
    __syncthreads();

    // single-wave exclusive scan over NROWS_PAD rows (13/lane)
    if (tid < 64) {
        int base = tid * 13;
        int pre[13];
        int sum = 0;
        #pragma unroll
        for (int j = 0; j < 13; j++) { pre[j] = sum; sum += roff[base + j]; }
        int incl = sum;
        #pragma unroll
        for (int off = 1; off < 64; off <<= 1) {
            int t = __shfl_up(incl, off, 64);
            if (tid >= off) incl += t;
        }
        int ex = incl - sum;
        #pragma unroll
        for (int j = 0; j < 13; j++)
            roff[base + j] = (unsigned short)(ex + pre[j]);
        if (tid == 63) sTotal = incl;
    }
    __syncthreads();
    if (tid == 0) roff[NROWS_PAD] = (unsigned short)sTotal;  // sentinel
    __syncthreads();

    int total = sTotal;
    float acc[9] = {0,0,0,0,0,0,0,0,0};
    int half = tid >> 7;          // 0: first half of records, 1: second half
    int atom = tid & (APB - 1);   // each atom owned by 2 threads

    for (int w0 = 0; w0 < total; w0 += CAP2) {
        int wend = min(w0 + CAP2, total);
        int nc = wend - w0;

        if (tid < APB) cnt[tid] = 0;
        __syncthreads();

        // gather (binary search, coalesced) + histogram-with-rank in one pass
        int key6[IT2], rnk6[IT2];   // static indices only — VGPRs
        #pragma unroll
        for (int it = 0; it < IT2; it++) {
            int i = it * 256 + tid;
            key6[it] = -1;
            rnk6[it] = 0;
            if (i < nc) {
                int p = w0 + i;
                int l = 0, h = nblocks;   // roff[l] <= p < roff[h]
                #pragma unroll 1
                while (h - l > 1) {
                    int m = (l + h) >> 1;
                    if ((int)roff[m] <= p) l = m; else h = m;
                }
                int j = p - (int)roff[l];
                int4 r = payload[(size_t)l * PH1_REC + (int)sst[l] + j];
                srec2[i] = r;
                int k = r.x & (APB - 1);
                key6[it] = k;
                rnk6[it] = atomicAdd(&cnt[k], 1);   // arrival rank
            }
        }
        __syncthreads();

        // single-wave exclusive scan over 128 keys (2/lane)
        if (tid < 64) {
            int c0 = cnt[2 * tid], c1 = cnt[2 * tid + 1];
            int s1 = c0 + c1;
            int incl = s1;
            #pragma unroll
            for (int off = 1; off < 64; off <<= 1) {
                int t = __shfl_up(incl, off, 64);
                if (tid >= off) incl += t;
            }
            int ex = incl - s1;
            aexcl[2 * tid]     = ex;
            aexcl[2 * tid + 1] = ex + c0;
        }
        __syncthreads();

        // scatter indices sorted by atom — NO atomic (slot = excl + rank)
        #pragma unroll
        for (int it = 0; it < IT2; it++) {
            if (key6[it] >= 0)
                sidx[aexcl[key6[it]] + rnk6[it]] =
                    (unsigned short)(it * 256 + tid);
        }
        __syncthreads();

        // accumulation: 2 threads per atom, each takes half the records
        {
            int st = aexcl[atom], n = cnt[atom];
            int mid = st + ((n + 1) >> 1);
            int lo = half ? mid : st;
            int hi = half ? (st + n) : mid;
            for (int j = lo; j < hi; j++) {
                int4 r = srec2[sidx[j]];
                float2 g01 = unpack2((unsigned)r.y);
                float2 g2t = unpack2((unsigned)r.z);
                float2 t12 = unpack2((unsigned)r.w);
                float g0 = g01.x, g1 = g01.y, g2 = g2t.x;
                float t0 = g2t.y, t1 = t12.x, t2 = t12.y;
                acc[0] += g0 * t0; acc[1] += g0 * t1; acc[2] += g0 * t2;
                acc[3] += g1 * t0; acc[4] += g1 * t1; acc[5] += g1 * t2;
                acc[6] += g2 * t0; acc[7] += g2 * t1; acc[8] += g2 * t2;
            }
        }
        __syncthreads();   // srec2/sidx reused next chunk
    }

    // combine the two halves and overwrite out (coalesced)
    if (half == 0) {
        #pragma unroll
        for (int k = 0; k < 9; k++) sout[atom * 9 + k] = acc[k];
    }
    __syncthreads();
    if (half == 1) {
        #pragma unroll
        for (int k = 0; k < 9; k++) sout[atom * 9 + k] += acc[k];
    }
    __syncthreads();
    size_t gbase = (size_t)b * APB * 9;
    size_t lim = (size_t)A * 9;
    for (int i = tid; i < APB * 9; i += 256) {
        size_t gi = gbase + i;
        if (gi < lim) out[gi] = sout[i];
    }
}

// Fallback: direct per-edge global atomics (correct, slow).
__global__ __launch_bounds__(256) void vb_edge_fallback(
    const float* __restrict__ vecs,
    const int*   __restrict__ centers,
    const int*   __restrict__ neighbors,
    const int*   __restrict__ species,
    const float* __restrict__ W_alch,
    const float* __restrict__ cemb,
    const float* __restrict__ Wc,
    float*       __restrict__ out,
    int E)
{
    __shared__ float sW2[3 * NRAD * 16];
    build_w2(sW2, cemb, Wc, W_alch, threadIdx.x, blockDim.x);
    __syncthreads();

    int e = blockIdx.x * blockDim.x + threadIdx.x;
    if (e >= E) return;
    float vx = vecs[3 * e + 0], vy = vecs[3 * e + 1], vz = vecs[3 * e + 2];
    int c = centers[e];
    int pair = species[c] * 4 + species[neighbors[e]];
    float g[3], t[3];
    if (!edge_math(vx, vy, vz, pair, sW2, g, t)) return;
    float* op = out + (size_t)c * 9;
    #pragma unroll
    for (int m = 0; m < 3; m++)
        #pragma unroll
        for (int o = 0; o < 3; o++)
            atomicAdd(op + m * 3 + o, g[m] * t[o]);
}

extern "C" void kernel_launch(void* const* d_in, const int* in_sizes, int n_in,
                              void* d_out, int out_size, void* d_ws, size_t ws_size,
                              hipStream_t stream) {
    const float* vecs      = (const float*)d_in[0];
    const int*   centers   = (const int*)d_in[1];
    const int*   neighbors = (const int*)d_in[2];
    const int*   species   = (const int*)d_in[3];
    const float* W_alch    = (const float*)d_in[6];
    const float* cemb      = (const float*)d_in[7];
    const float* Wc        = (const float*)d_in[8];
    float*       out       = (float*)d_out;

    int E = in_sizes[1];
    int A = in_sizes[3];
    int nbin    = (A + APB - 1) >> APB_SH;
    int nblocks = (E + PH1_REC - 1) / PH1_REC;

    // ws: [runoff nblocks*RS u16][payload nblocks*2048*16B]
    size_t ro_bytes = ((size_t)nblocks * RS * 2 + 255) & ~(size_t)255;
    size_t need = ro_bytes + (size_t)nblocks * PH1_REC * 16;

    if (nbin + 1 <= RS && nbin <= NBIN_PAD && nblocks <= NROWS_PAD &&
        need <= ws_size) {
        unsigned short* runoff = (unsigned short*)d_ws;
        int4* payload = (int4*)((char*)d_ws + ro_bytes);

        vb_phase1<<<nblocks, PH1_BLK, 0, stream>>>(vecs, centers, neighbors,
                                                   species, W_alch, cemb, Wc,
                                                   runoff, payload, E, nbin);
        vb_phase2<<<nbin, 256, 0, stream>>>(runoff, payload, out, A, nblocks);
    } else {
        hipMemsetAsync(d_out, 0, (size_t)out_size * sizeof(float), stream);
        int grid = (E + 255) / 256;
        vb_edge_fallback<<<grid, 256, 0, stream>>>(vecs, centers, neighbors,
                                                   species, W_alch, cemb, Wc,
                                                   out, E);
    }
}